// Round 16
// baseline (89.298 us; speedup 1.0000x reference)
//
#include <hip/hip_runtime.h>

// ---------- types ----------
typedef __attribute__((ext_vector_type(8)))  __bf16 bf16x8;
typedef __attribute__((ext_vector_type(4)))  float  f32x4;

// ---------- helpers ----------
__device__ __forceinline__ short f2bf(float f) {
    unsigned u = __builtin_bit_cast(unsigned, f);
    unsigned r = (u + 0x7fffu + ((u >> 16) & 1u)) >> 16;   // RNE
    return (short)r;
}
__device__ __forceinline__ float lo16(unsigned u) { return __builtin_bit_cast(float, u << 16); }
__device__ __forceinline__ float hi16(unsigned u) { return __builtin_bit_cast(float, u & 0xffff0000u); }

__device__ __forceinline__ void gload16(const void* g, void* l) {
    __builtin_amdgcn_global_load_lds(
        (const __attribute__((address_space(1))) unsigned*)g,
        (__attribute__((address_space(3))) unsigned*)l, 16, 0, 0);
}

// rope a pair of 8-element bf16 chunks (packed in uint4), cs8[e] = (cos,sin) for elem e
__device__ __forceinline__ void ropePair(const uint4& a, const uint4& b,
                                         const float2* cs8, float scale,
                                         uint4& oa, uint4& ob) {
    const unsigned au[4] = {a.x, a.y, a.z, a.w}, bu[4] = {b.x, b.y, b.z, b.w};
    unsigned ra[4], rb[4];
    #pragma unroll
    for (int wi = 0; wi < 4; ++wi) {
        const float x1l = lo16(au[wi]), x1h = hi16(au[wi]);
        const float x2l = lo16(bu[wi]), x2h = hi16(bu[wi]);
        const float2 cl = cs8[wi * 2], ch = cs8[wi * 2 + 1];
        const float o1l = (x1l * cl.x - x2l * cl.y) * scale;
        const float o2l = (x1l * cl.y + x2l * cl.x) * scale;
        const float o1h = (x1h * ch.x - x2h * ch.y) * scale;
        const float o2h = (x1h * ch.y + x2h * ch.x) * scale;
        ra[wi] = (unsigned)(unsigned short)f2bf(o1l) | ((unsigned)(unsigned short)f2bf(o1h) << 16);
        rb[wi] = (unsigned)(unsigned short)f2bf(o2l) | ((unsigned)(unsigned short)f2bf(o2h) << 16);
    }
    oa = make_uint4(ra[0], ra[1], ra[2], ra[3]);
    ob = make_uint4(rb[0], rb[1], rb[2], rb[3]);
}

// ---------- constants ----------
#define S_LEN   2048
#define MAT_ELEMS 4194304     // 4096*1024
#define VT_ROW  2176          // 128 zero-pad + 2048 keys
#define VT_MAT  2228224       // 1024 * VT_ROW

// ---------- prep: fp32->bf16 converts + rope table + bias cat + vt pad zero ----------
__global__ __launch_bounds__(256) void prep(
    const float* __restrict__ x,  const float* __restrict__ Wq,
    const float* __restrict__ Wk, const float* __restrict__ Wv,
    const float* __restrict__ Wo, const float* __restrict__ bq,
    const float* __restrict__ bk, const float* __restrict__ bv,
    short* __restrict__ xb, short* __restrict__ wcat, short* __restrict__ wob,
    float* __restrict__ bcat, float2* __restrict__ tab, short* __restrict__ vt)
{
    const int tid = blockIdx.x * 256 + threadIdx.x;   // 0 .. 2M-1 (float4 units)
    const float4* src;
    short* dst;
    if (tid < 1048576) {                       // x: 4M floats
        src = (const float4*)x + tid;  dst = xb + (size_t)tid * 4;
    } else if (tid < 1835008) {                // Wq|Wk|Wv: 3M floats
        const int o = tid - 1048576;
        const int mat = o >> 18;
        const int wi  = o & 262143;
        const float* W = (mat == 0) ? Wq : (mat == 1) ? Wk : Wv;
        src = (const float4*)W + wi;  dst = wcat + (size_t)o * 4;
    } else {                                   // Wo: 1M floats
        const int o = tid - 1835008;
        src = (const float4*)Wo + o;  dst = wob + (size_t)o * 4;
    }
    const float4 v = *src;
    short4 s4 = make_short4(f2bf(v.x), f2bf(v.y), f2bf(v.z), f2bf(v.w));
    *(short4*)dst = s4;

    if (tid < 65536) {                         // rope table [2048][32]
        const int s  = tid >> 5;
        const int jr = tid & 31;
        const float freq = exp2f(-(float)jr * (13.287712379549449f / 32.0f)); // 10000^(-jr/32)
        const float ang  = (float)s * freq;
        tab[tid] = make_float2(cosf(ang), sinf(ang));
    }
    if (tid < 768) {                           // bias cat [3][1024] fp32
        const float* B = (tid < 256) ? bq : (tid < 512) ? bk : bv;
        ((float4*)bcat)[tid] = ((const float4*)B)[tid & 255];
    }
    if (tid < 16384) {                         // zero vt pad: [2048 rows][128]
        const int row = tid >> 3, ch = tid & 7;
        *(uint4*)&vt[(size_t)row * VT_ROW + ch * 8] = make_uint4(0, 0, 0, 0);
    }
}

// ---------- 128(M)x64(N) high-occupancy GEMM for QKV (B^T layout) ----------
// gemm_out's proven structure (measured ~716 TF at 2+ blocks/CU via inter-
// block TLP) applied to the QKV GEMM: 256 thr / 4 waves, 24 KB LDS ->
// 6 blocks/CU, grid 32x48 = 1536. R15 lesson: intra-block pipelining at
// 1 block/CU is barrier-bound (8-phase made it WORSE); occupancy is the
// lever our register budget allows. XOR-swizzled staging (conflicts 0).
// XCD swizzle: per XCD 4 M-rows x 48 N-cols (A ~1 MB L2-resident, B streams).
__global__ __launch_bounds__(256) void gemm8(
    const short* __restrict__ A,   // [4096][1024]
    const short* __restrict__ Bw,  // [3072][1024] (row = out col)
    const float* __restrict__ bias,// [3072] (bcat)
    short* __restrict__ outb,      // Q,K: [2][4096][1024]
    short* __restrict__ vt)        // V^T: [2][1024][2176] (128-key zero pad front)
{
    __shared__ short As[128 * 64];   // [row][k], XOR-swizzled contents
    __shared__ short Bs[64 * 64];
    const int tid  = threadIdx.x;
    const int w    = tid >> 6, lane = tid & 63;
    const int lr   = lane & 15, lg = lane >> 4;

    // XCD swizzle: 1536 = 8 XCD * 192; per-XCD 4 M-rows x 48 N-cols (bijective)
    const int wg  = blockIdx.x;
    const int xcd = wg & 7, i6 = wg >> 3;
    const int by  = xcd * 4 + i6 / 48, bx = i6 % 48;
    const int row0 = by * 128, col0 = bx * 64;

    // hoisted per-lane staging address (pre-swizzled source col)
    const int scl = ((lane & 7) * 16) ^ (((lane >> 3) & 7) << 4);
    const char* gA = (const char*)A  + (size_t)(row0 + w * 32) * 2048 + (lane >> 3) * 2048 + scl;
    const char* gB = (const char*)Bw + (size_t)(col0 + w * 16) * 2048 + (lane >> 3) * 2048 + scl;
    const int cswz0 = (lg * 16)      ^ ((lr & 7) << 4);
    const int cswz1 = (64 + lg * 16) ^ ((lr & 7) << 4);

    f32x4 acc[2][4] = {};

    for (int kt = 0; kt < 16; ++kt) {
        __syncthreads();
        #pragma unroll
        for (int rr = 0; rr < 4; ++rr)       // A: wave stages rows w*32 .. w*32+31
            gload16(gA + rr * 16384 + kt * 128, (short*)As + (w * 32 + rr * 8) * 64);
        #pragma unroll
        for (int rr = 0; rr < 2; ++rr)       // B: wave stages rows w*16 .. w*16+15
            gload16(gB + rr * 16384 + kt * 128, (short*)Bs + (w * 16 + rr * 8) * 64);
        __syncthreads();                     // compiler drains vmcnt before barrier
        #pragma unroll
        for (int kk = 0; kk < 2; ++kk) {
            const int cs = kk ? cswz1 : cswz0;
            bf16x8 af[2], bf[4];
            #pragma unroll
            for (int i = 0; i < 2; ++i)
                af[i] = *(const bf16x8*)((const char*)As + (w * 32 + i * 16 + lr) * 128 + cs);
            #pragma unroll
            for (int j = 0; j < 4; ++j)
                bf[j] = *(const bf16x8*)((const char*)Bs + (j * 16 + lr) * 128 + cs);
            #pragma unroll
            for (int i = 0; i < 2; ++i)
                #pragma unroll
                for (int j = 0; j < 4; ++j)
                    acc[i][j] = __builtin_amdgcn_mfma_f32_16x16x32_bf16(af[i], bf[j], acc[i][j], 0, 0, 0);
        }
    }

    // epilogue: 64-col tile lies within one mat (64 | 1024)
    const int mat = col0 >> 10;
    const int cm0 = col0 & 1023;
    if (mat == 2) {                          // V^T: vt[b][dg][128+key], 8B stores
        #pragma unroll
        for (int j = 0; j < 4; ++j) {
            const int co = j * 16 + lr;
            const float bb = bias[col0 + co];
            const size_t dgo = (size_t)(cm0 + co) * VT_ROW;
            #pragma unroll
            for (int i = 0; i < 2; ++i) {
                const int rg = row0 + w * 32 + i * 16 + lg * 4;
                const int bq_ = rg >> 11, key = rg & 2047;
                short4 sv;
                sv.x = f2bf(acc[i][j][0] + bb); sv.y = f2bf(acc[i][j][1] + bb);
                sv.z = f2bf(acc[i][j][2] + bb); sv.w = f2bf(acc[i][j][3] + bb);
                *(short4*)&vt[(size_t)bq_ * VT_MAT + dgo + 128 + key] = sv;
            }
        }
    } else {                                 // Q/K rows
        short* outm = outb + (size_t)mat * MAT_ELEMS;
        #pragma unroll
        for (int j = 0; j < 4; ++j) {
            const int co = cm0 + j * 16 + lr;
            const float bb = bias[col0 + j * 16 + lr];
            #pragma unroll
            for (int i = 0; i < 2; ++i) {
                const int rg = row0 + w * 32 + i * 16 + lg * 4;
                #pragma unroll
                for (int r = 0; r < 4; ++r)
                    outm[(size_t)(rg + r) * 1024 + co] = f2bf(acc[i][j][r] + bb);
            }
        }
    }
}

// ---------- 128(M)x64(N) GEMM for out-proj (fp32 out + bias) ----------
__global__ __launch_bounds__(256) void gemm_out(
    const short* __restrict__ A, const short* __restrict__ Bw,
    const float* __restrict__ bias, float* __restrict__ outf)
{
    __shared__ short As[128 * 64];   // [row][k]
    __shared__ short Bs[64 * 64];    // [col][k]
    const int tid  = threadIdx.x;
    const int w    = tid >> 6, lane = tid & 63;
    const int row0 = blockIdx.y * 128, col0 = blockIdx.x * 64;
    const int lr   = lane & 15, lg = lane >> 4;
    const int srow = lane >> 3, scol = (lane & 7) * 8;

    f32x4 acc[2][4] = {};

    for (int kt = 0; kt < 16; ++kt) {
        const int k0 = kt * 64;
        __syncthreads();
        #pragma unroll
        for (int rr = 0; rr < 4; ++rr) {
            const int r = w * 32 + rr * 8;
            gload16(A + (size_t)(row0 + r + srow) * 1024 + k0 + scol, (short*)As + r * 64);
        }
        #pragma unroll
        for (int rr = 0; rr < 2; ++rr) {
            const int r = w * 16 + rr * 8;
            gload16(Bw + (size_t)(col0 + r + srow) * 1024 + k0 + scol, (short*)Bs + r * 64);
        }
        __syncthreads();
        #pragma unroll
        for (int kk = 0; kk < 2; ++kk) {
            const int kb = kk * 32 + lg * 8;
            bf16x8 af[2], bf[4];
            #pragma unroll
            for (int i = 0; i < 2; ++i)
                af[i] = *(const bf16x8*)&As[(w * 32 + i * 16 + lr) * 64 + kb];
            #pragma unroll
            for (int j = 0; j < 4; ++j)
                bf[j] = *(const bf16x8*)&Bs[(j * 16 + lr) * 64 + kb];
            #pragma unroll
            for (int i = 0; i < 2; ++i)
                #pragma unroll
                for (int j = 0; j < 4; ++j)
                    acc[i][j] = __builtin_amdgcn_mfma_f32_16x16x32_bf16(af[i], bf[j], acc[i][j], 0, 0, 0);
        }
    }

    #pragma unroll
    for (int i = 0; i < 2; ++i) {
        const int grb = row0 + w * 32 + i * 16 + lg * 4;
        #pragma unroll
        for (int j = 0; j < 4; ++j) {
            const int cm = col0 + j * 16 + lr;
            const float bb = bias[cm];
            #pragma unroll
            for (int r = 0; r < 4; ++r)
                outf[(size_t)(grb + r) * 1024 + cm] = acc[i][j][r] + bb;
        }
    }
}

// ---------- MFMA sliding-window attention: 128 queries/block, 8 waves ----------
// (unchanged from R14 — verified PASS; V^T col clamped to 248 so zero-P frags
// never over-read past the 256-key row.)
#define KS_ST 72
#define P_ST  168
__global__ __launch_bounds__(512) void attn_mfma(const short* __restrict__ qkv,
                                                 const short* __restrict__ vt,
                                                 short* __restrict__ ctx,
                                                 const float2* __restrict__ tab)
{
    __shared__ char lds[76800];
    short* Ks  = (short*)lds;                    // [256][72] = 36864 B
    short* Pl  = (short*)lds;                    // union: [8][16][168] = 43008 B
    char*  VTs = lds + 43008;                    // [64 d][512 B] = 32768 B
    float* linv = (float*)(lds + 75776);         // [8][16]

    const int tid = threadIdx.x;                 // 0..511
    const int w = tid >> 6, lane = tid & 63;     // 8 waves
    const int g = lane >> 4, l15 = lane & 15;
    const int phys = blockIdx.x;                 // 0..511
    const int bid = (phys & 7) * 64 + (phys >> 3);   // XCD-pack (b,h) groups
    const int b  = bid >> 8;
    const int h  = (bid >> 4) & 15;
    const int qb = bid & 15;
    const int qs = qb << 7;                      // 128-query tile
    const size_t rowbase = (size_t)b * S_LEN;
    const int hc = h << 6;

    // --- stage V^T tile [64 d][256 keys] coalesced, swizzled source ---
    const short* vhead = vt + ((size_t)b * 1024 + h * 64) * VT_ROW + qs;  // +128 pad = key qs-128
    #pragma unroll
    for (int rdx = 0; rdx < 4; ++rdx) {
        const int c = rdx * 512 + tid;           // 0..2047
        const int row = c >> 5, ch = c & 31;     // 64 rows x 32 chunks of 16 B
        const int srcb = (ch * 16) ^ ((row & 7) << 4);
        gload16((const char*)(vhead + (size_t)row * VT_ROW) + srcb, VTs + c * 16);
    }

    // --- stage K with rope (pairs (c, c+32)), zero rows gk<0, stride 72 ---
    #pragma unroll
    for (int it = 0; it < 2; ++it) {
        const int c   = it * 512 + tid;          // 1024 pair-tasks (256 keys x 4)
        const int key = c >> 2;
        const int jb  = (c & 3) << 3;            // 0,8,16,24
        const int gk  = qs - 128 + key;
        const int gkc = gk < 0 ? 0 : gk;
        const short* kb = qkv + (size_t)1 * MAT_ELEMS + (rowbase + gkc) * 1024 + hc;
        const uint4 k1 = *(const uint4*)(kb + jb);
        const uint4 k2 = *(const uint4*)(kb + jb + 32);
        uint4 o1, o2;
        ropePair(k1, k2, tab + (size_t)gkc * 32 + jb, 1.0f, o1, o2);
        if (gk < 0) { o1 = make_uint4(0, 0, 0, 0); o2 = make_uint4(0, 0, 0, 0); }
        *(uint4*)&Ks[key * KS_ST + jb]      = o1;
        *(uint4*)&Ks[key * KS_ST + jb + 32] = o2;
    }
    __syncthreads();                             // K + V^T staged (vmcnt drained)

    // --- Q frags from global, rope + 0.125 scale ---
    const int q = qs + 16 * w + l15;
    const size_t qoff = (rowbase + q) * 1024 + hc;
    const uint4 q1 = *(const uint4*)&qkv[qoff + g * 8];
    const uint4 q2 = *(const uint4*)&qkv[qoff + 32 + g * 8];
    uint4 r1, r2;
    ropePair(q1, q2, tab + (size_t)q * 32 + g * 8, 0.125f, r1, r2);
    const bf16x8 qf0 = __builtin_bit_cast(bf16x8, r1);
    const bf16x8 qf1 = __builtin_bit_cast(bf16x8, r2);

    // --- QK^T: S[q=4g+r][jj=16t+l15]; wave w keys = rows 16w..16w+143 ---
    f32x4 st[9];
    #pragma unroll
    for (int t = 0; t < 9; ++t) {
        const int krow = 16 * w + 16 * t + l15;
        bf16x8 kf0 = *(const bf16x8*)&Ks[krow * KS_ST + g * 8];
        bf16x8 kf1 = *(const bf16x8*)&Ks[krow * KS_ST + 32 + g * 8];
        f32x4 a = {0.f, 0.f, 0.f, 0.f};
        a = __builtin_amdgcn_mfma_f32_16x16x32_bf16(qf0, kf0, a, 0, 0, 0);
        a = __builtin_amdgcn_mfma_f32_16x16x32_bf16(qf1, kf1, a, 0, 0, 0);
        st[t] = a;
    }
    __syncthreads();                             // all Ks reads done; P may overwrite

    // --- softmax (row q = 4g+r held across st[t][r]) + P write (wave-private) ---
    const int jmin = 128 - qs - 16 * w;
    float mrow[4], lsum[4];
    #pragma unroll
    for (int r = 0; r < 4; ++r) mrow[r] = -3.0e38f;
    #pragma unroll
    for (int t = 0; t < 9; ++t) {
        const int jj = 16 * t + l15;
        #pragma unroll
        for (int r = 0; r < 4; ++r) {
            const int qi = 4 * g + r;
            const bool ok = (jj >= qi) && (jj <= qi + 128) && (jj >= jmin);
            if (ok) mrow[r] = fmaxf(mrow[r], st[t][r]);
        }
    }
    #pragma unroll
    for (int r = 0; r < 4; ++r) {
        mrow[r] = fmaxf(mrow[r], __shfl_xor(mrow[r], 1));
        mrow[r] = fmaxf(mrow[r], __shfl_xor(mrow[r], 2));
        mrow[r] = fmaxf(mrow[r], __shfl_xor(mrow[r], 4));
        mrow[r] = fmaxf(mrow[r], __shfl_xor(mrow[r], 8));
        lsum[r] = 0.0f;
    }
    short* Pw = Pl + w * (16 * P_ST);
    #pragma unroll
    for (int t = 0; t < 9; ++t) {
        const int jj = 16 * t + l15;
        #pragma unroll
        for (int r = 0; r < 4; ++r) {
            const int qi = 4 * g + r;
            const bool ok = (jj >= qi) && (jj <= qi + 128) && (jj >= jmin);
            const float p = ok ? __expf(st[t][r] - mrow[r]) : 0.0f;
            lsum[r] += p;
            Pw[qi * P_ST + jj] = f2bf(p);
        }
    }
    {
        short4 z = make_short4(0, 0, 0, 0);
        *(short4*)&Pw[l15 * P_ST + 144 + 4 * g] = z;
    }
    #pragma unroll
    for (int r = 0; r < 4; ++r) {
        lsum[r] += __shfl_xor(lsum[r], 1);
        lsum[r] += __shfl_xor(lsum[r], 2);
        lsum[r] += __shfl_xor(lsum[r], 4);
        lsum[r] += __shfl_xor(lsum[r], 8);
        if (l15 == r) linv[w * 16 + 4 * g + r] = 1.0f / lsum[r];
    }
    // no barrier: P/linv written and read by the same wave

    // --- PV: O^T[d][q] = sum_key V^T[d][key] * P[q][key], V^T from LDS ---
    f32x4 oc[4] = {};
    #pragma unroll
    for (int kc = 0; kc < 5; ++kc) {
        bf16x8 pf = *(const bf16x8*)&Pw[l15 * P_ST + kc * 32 + g * 8];
        int cole = 16 * w + kc * 32 + g * 8;     // V^T element col
        if (cole > 248) cole = 248;              // clamp: only zero-P frags
        const int colb = cole * 2;               // byte col in VTs row
        #pragma unroll
        for (int dt = 0; dt < 4; ++dt) {
            const int row = dt * 16 + l15;
            bf16x8 vf = *(const bf16x8*)(VTs + row * 512 + (colb ^ ((row & 7) << 4)));
            oc[dt] = __builtin_amdgcn_mfma_f32_16x16x32_bf16(vf, pf, oc[dt], 0, 0, 0);
        }
    }

    // --- store: lane holds O[q=l15][dt*16 + 4g + 0..3] ---
    const float inv = linv[w * 16 + l15];
    #pragma unroll
    for (int dt = 0; dt < 4; ++dt) {
        short4 sv;
        sv.x = f2bf(oc[dt][0] * inv);
        sv.y = f2bf(oc[dt][1] * inv);
        sv.z = f2bf(oc[dt][2] * inv);
        sv.w = f2bf(oc[dt][3] * inv);
        *(short4*)&ctx[(rowbase + qs + 16 * w + l15) * 1024 + hc + dt * 16 + 4 * g] = sv;
    }
}

// ---------- launch ----------
extern "C" void kernel_launch(void* const* d_in, const int* in_sizes, int n_in,
                              void* d_out, int out_size, void* d_ws, size_t ws_size,
                              hipStream_t stream) {
    const float* x  = (const float*)d_in[0];
    const float* Wq = (const float*)d_in[1];
    const float* bq = (const float*)d_in[2];
    const float* Wk = (const float*)d_in[3];
    const float* bk = (const float*)d_in[4];
    const float* Wv = (const float*)d_in[5];
    const float* bv = (const float*)d_in[6];
    const float* Wo = (const float*)d_in[7];
    const float* bo = (const float*)d_in[8];

    char* ws = (char*)d_ws;
    short*  xb   = (short*) (ws + 0);          //  8 MiB  x bf16 (dead after gemm8)
    short*  ctx  = (short*) (ws + 0);          //  8 MiB  attn out (reuses xb region)
    short*  wcat = (short*) (ws + 8388608);    //  6 MiB  Wq|Wk|Wv bf16
    short*  wob  = (short*) (ws + 14680064);   //  2 MiB  Wo bf16
    short*  qkv  = (short*) (ws + 16777216);   // 16 MiB  q|k bf16 (roped in attn)
    short*  vt   = (short*) (ws + 33554432);   //  8.5 MiB V^T [2][1024][2176]
    float2* tab  = (float2*)(ws + 42467328);   // 512 KiB rope cos/sin
    float*  bcat = (float*) (ws + 42991616);   // 12 KiB  bq|bk|bv

    prep<<<8192, 256, 0, stream>>>(x, Wq, Wk, Wv, Wo, bq, bk, bv,
                                   xb, wcat, wob, bcat, tab, vt);
    gemm8<<<1536, 256, 0, stream>>>(xb, wcat, bcat, qkv, vt);
    attn_mfma<<<512, 512, 0, stream>>>(qkv, vt, ctx, tab);
    gemm_out<<<dim3(16, 32), 256, 0, stream>>>(ctx, wob, bo, (float*)d_out);
}

// Round 17
// 77.919 us; speedup vs baseline: 1.1460x; 1.1460x over previous
//
#include <hip/hip_runtime.h>

// ---------- types ----------
typedef __attribute__((ext_vector_type(8)))  __bf16 bf16x8;
typedef __attribute__((ext_vector_type(4)))  float  f32x4;

// ---------- helpers ----------
__device__ __forceinline__ short f2bf(float f) {
    unsigned u = __builtin_bit_cast(unsigned, f);
    unsigned r = (u + 0x7fffu + ((u >> 16) & 1u)) >> 16;   // RNE
    return (short)r;
}
__device__ __forceinline__ float lo16(unsigned u) { return __builtin_bit_cast(float, u << 16); }
__device__ __forceinline__ float hi16(unsigned u) { return __builtin_bit_cast(float, u & 0xffff0000u); }

__device__ __forceinline__ void gload16(const void* g, void* l) {
    __builtin_amdgcn_global_load_lds(
        (const __attribute__((address_space(1))) unsigned*)g,
        (__attribute__((address_space(3))) unsigned*)l, 16, 0, 0);
}

// rope a pair of 8-element bf16 chunks (packed in uint4), cs8[e] = (cos,sin) for elem e
__device__ __forceinline__ void ropePair(const uint4& a, const uint4& b,
                                         const float2* cs8, float scale,
                                         uint4& oa, uint4& ob) {
    const unsigned au[4] = {a.x, a.y, a.z, a.w}, bu[4] = {b.x, b.y, b.z, b.w};
    unsigned ra[4], rb[4];
    #pragma unroll
    for (int wi = 0; wi < 4; ++wi) {
        const float x1l = lo16(au[wi]), x1h = hi16(au[wi]);
        const float x2l = lo16(bu[wi]), x2h = hi16(bu[wi]);
        const float2 cl = cs8[wi * 2], ch = cs8[wi * 2 + 1];
        const float o1l = (x1l * cl.x - x2l * cl.y) * scale;
        const float o2l = (x1l * cl.y + x2l * cl.x) * scale;
        const float o1h = (x1h * ch.x - x2h * ch.y) * scale;
        const float o2h = (x1h * ch.y + x2h * ch.x) * scale;
        ra[wi] = (unsigned)(unsigned short)f2bf(o1l) | ((unsigned)(unsigned short)f2bf(o1h) << 16);
        rb[wi] = (unsigned)(unsigned short)f2bf(o2l) | ((unsigned)(unsigned short)f2bf(o2h) << 16);
    }
    oa = make_uint4(ra[0], ra[1], ra[2], ra[3]);
    ob = make_uint4(rb[0], rb[1], rb[2], rb[3]);
}

// ---------- constants ----------
#define S_LEN   2048
#define MAT_ELEMS 4194304     // 4096*1024
#define VT_ROW  2176          // 128 zero-pad + 2048 keys
#define VT_MAT  2228224       // 1024 * VT_ROW

// ---------- prep: fp32->bf16 converts + rope table + bias cat + vt pad zero ----------
__global__ __launch_bounds__(256) void prep(
    const float* __restrict__ x,  const float* __restrict__ Wq,
    const float* __restrict__ Wk, const float* __restrict__ Wv,
    const float* __restrict__ Wo, const float* __restrict__ bq,
    const float* __restrict__ bk, const float* __restrict__ bv,
    short* __restrict__ xb, short* __restrict__ wcat, short* __restrict__ wob,
    float* __restrict__ bcat, float2* __restrict__ tab, short* __restrict__ vt)
{
    const int tid = blockIdx.x * 256 + threadIdx.x;   // 0 .. 2M-1 (float4 units)
    const float4* src;
    short* dst;
    if (tid < 1048576) {                       // x: 4M floats
        src = (const float4*)x + tid;  dst = xb + (size_t)tid * 4;
    } else if (tid < 1835008) {                // Wq|Wk|Wv: 3M floats
        const int o = tid - 1048576;
        const int mat = o >> 18;
        const int wi  = o & 262143;
        const float* W = (mat == 0) ? Wq : (mat == 1) ? Wk : Wv;
        src = (const float4*)W + wi;  dst = wcat + (size_t)o * 4;
    } else {                                   // Wo: 1M floats
        const int o = tid - 1835008;
        src = (const float4*)Wo + o;  dst = wob + (size_t)o * 4;
    }
    const float4 v = *src;
    short4 s4 = make_short4(f2bf(v.x), f2bf(v.y), f2bf(v.z), f2bf(v.w));
    *(short4*)dst = s4;

    if (tid < 65536) {                         // rope table [2048][32]
        const int s  = tid >> 5;
        const int jr = tid & 31;
        const float freq = exp2f(-(float)jr * (13.287712379549449f / 32.0f)); // 10000^(-jr/32)
        const float ang  = (float)s * freq;
        tab[tid] = make_float2(cosf(ang), sinf(ang));
    }
    if (tid < 768) {                           // bias cat [3][1024] fp32
        const float* B = (tid < 256) ? bq : (tid < 512) ? bk : bv;
        ((float4*)bcat)[tid] = ((const float4*)B)[tid & 255];
    }
    if (tid < 16384) {                         // zero vt pad: [2048 rows][128]
        const int row = tid >> 3, ch = tid & 7;
        *(uint4*)&vt[(size_t)row * VT_ROW + ch * 8] = make_uint4(0, 0, 0, 0);
    }
}

// ---------- 256(M)x192(N) 2-barrier pipelined GEMM for QKV (B^T layout) ----------
// R14 version (measured best: 41.7 us, WRITE clean, conflicts 0). Six
// structural variants (deep pipeline, tail-load, 8-phase, high-occupancy)
// all measured equal-or-worse -> this is the lineage optimum at K=1024.
#define VMC4 do { asm volatile("s_waitcnt vmcnt(4)" ::: "memory"); __builtin_amdgcn_sched_barrier(0); } while (0)
#define VMC0 do { asm volatile("s_waitcnt vmcnt(0)" ::: "memory"); __builtin_amdgcn_sched_barrier(0); } while (0)
#define BAR  __builtin_amdgcn_s_barrier()
#define SB   __builtin_amdgcn_sched_barrier(0)

#define LDA_ALL(T) _Pragma("unroll") for (int ii = 0; ii < 4; ++ii) { \
    aF[ii][0] = ldf(T, fA0, ii * 2048);                                \
    aF[ii][1] = ldf(T, fA1, ii * 2048); }
#define LDB0(T) _Pragma("unroll") for (int jj = 0; jj < 3; ++jj) {    \
    b0[jj][0] = ldf(T, fB0, jj * 2048);                                \
    b0[jj][1] = ldf(T, fB1, jj * 2048); }
#define LDB1(T) _Pragma("unroll") for (int jj = 0; jj < 3; ++jj) {    \
    b1[jj][0] = ldf(T, fB0, (jj + 3) * 2048);                          \
    b1[jj][1] = ldf(T, fB1, (jj + 3) * 2048); }

#define MFMA_HALF(JB, BQ)                                                     \
  __builtin_amdgcn_s_setprio(1);                                              \
  _Pragma("unroll") for (int ii = 0; ii < 4; ++ii)                            \
    _Pragma("unroll") for (int jj = 0; jj < 3; ++jj) {                        \
      acc[ii][(JB)+jj] = __builtin_amdgcn_mfma_f32_16x16x32_bf16(             \
          aF[ii][0], BQ[jj][0], acc[ii][(JB)+jj], 0, 0, 0);                   \
      acc[ii][(JB)+jj] = __builtin_amdgcn_mfma_f32_16x16x32_bf16(             \
          aF[ii][1], BQ[jj][1], acc[ii][(JB)+jj], 0, 0, 0);                   \
    }                                                                         \
  __builtin_amdgcn_s_setprio(0);

#define STGA(KT_, TILE) _Pragma("unroll") for (int g = 0; g < 4; ++g)  \
    gload16(gA + g * 16384 + (KT_) * 128, (TILE) + (w * 32 + g * 8) * 64);
#define STGB(KT_, TILE) _Pragma("unroll") for (int g = 0; g < 3; ++g)  \
    gload16(gB + g * 16384 + (KT_) * 128, (TILE) + (w * 24 + g * 8) * 64);

#define KT2(CA, CB, SBSTG, SASTG, WSTMT)              \
  LDA_ALL(CA); LDB0(CB); SBSTG;                       \
  MFMA_HALF(0, b0); SB; LDB1(CB); SB;                 \
  BAR;                                                \
  SASTG;                                              \
  MFMA_HALF(3, b1); WSTMT; BAR;

__global__ __launch_bounds__(512) void gemm8(
    const short* __restrict__ A,   // [4096][1024]
    const short* __restrict__ Bw,  // [3072][1024] (row = out col)
    const float* __restrict__ bias,// [3072]
    short* __restrict__ outb,      // Q,K: [2][4096][1024]
    short* __restrict__ vt)        // V^T: [2][1024][2176] (128-key zero pad front)
{
    __shared__ short lds[57344];               // 112 KiB
    short* const Ab0 = lds;                    // [256][64]
    short* const Bb0 = lds + 16384;            // [192][64]
    short* const Ab1 = lds + 28672;
    short* const Bb1 = lds + 45056;

    const int tid = threadIdx.x;
    const int w = tid >> 6, lane = tid & 63;
    const int wm = w >> 1, wn = w & 1;         // 4M x 2N
    const int lr = lane & 15, lg = lane >> 4;

    // XCD-aware swizzle: 256 = 8 * 32 (bijective)
    const int wg  = blockIdx.x;
    const int swz = (wg & 7) * 32 + (wg >> 3);
    const int bx = swz & 15, by = swz >> 4;
    const int row0 = by * 256, col0 = bx * 192;

    // ---- hoisted per-lane invariant addressing ----
    const int scl  = ((lane & 7) * 16) ^ (((lane >> 3) & 7) << 4);
    const int goff = (lane >> 3) * 2048 + scl;
    const char* gA = (const char*)A  + (size_t)(row0 + w * 32) * 2048 + goff;
    const char* gB = (const char*)Bw + (size_t)(col0 + w * 24) * 2048 + goff;
    const int cswz0 = (lg * 16)      ^ ((lr & 7) << 4);
    const int cswz1 = (64 + lg * 16) ^ ((lr & 7) << 4);
    const int fA0 = (wm * 64 + lr) * 128 + cswz0;
    const int fA1 = (wm * 64 + lr) * 128 + cswz1;
    const int fB0 = (wn * 96 + lr) * 128 + cswz0;
    const int fB1 = (wn * 96 + lr) * 128 + cswz1;

    auto ldf = [&](const short* buf, int voff, int imm) -> bf16x8 {
        return *(const bf16x8*)((const char*)buf + voff + imm);
    };

    f32x4 acc[4][6] = {};
    bf16x8 aF[4][2], b0[3][2], b1[3][2];

    // prologue: tile0 A,B + tile1 A
    STGA(0, Ab0); STGB(0, Bb0); STGA(1, Ab1);
    VMC4;
    BAR;

    #pragma unroll 1
    for (int it = 0; it < 7; ++it) {
        const int t0 = it * 2;
        KT2(Ab0, Bb0, STGB(t0 + 1, Bb1), STGA(t0 + 2, Ab0), VMC4)
        const int t1 = t0 + 1;
        KT2(Ab1, Bb1, STGB(t1 + 1, Bb0), STGA(t1 + 2, Ab1), VMC4)
    }
    KT2(Ab0, Bb0, STGB(15, Bb1), {}, VMC0)
    KT2(Ab1, Bb1, {}, {}, {})

    // epilogue: per-frag mat select (16-aligned frag base -> wave-uniform)
    #pragma unroll
    for (int j = 0; j < 6; ++j) {
        const int base_cm = col0 + wn * 96 + j * 16;
        const int matj = base_cm >> 10;
        const float bb = bias[base_cm + lr];
        if (matj == 2) {                       // V^T: vt[b][dg][128+key]
            const size_t dgo = (size_t)(base_cm - 2048 + lr) * VT_ROW;
            #pragma unroll
            for (int i = 0; i < 4; ++i) {
                const int rg = row0 + wm * 64 + i * 16 + lg * 4;
                const int bq_ = rg >> 11, key = rg & 2047;
                short4 sv;
                sv.x = f2bf(acc[i][j][0] + bb); sv.y = f2bf(acc[i][j][1] + bb);
                sv.z = f2bf(acc[i][j][2] + bb); sv.w = f2bf(acc[i][j][3] + bb);
                *(short4*)&vt[(size_t)bq_ * VT_MAT + dgo + 128 + key] = sv;
            }
        } else {                               // Q/K rows
            short* outm = outb + (size_t)matj * MAT_ELEMS;
            const int cmod = (base_cm & 1023) + lr;
            #pragma unroll
            for (int i = 0; i < 4; ++i) {
                const int rg = row0 + wm * 64 + i * 16 + lg * 4;
                #pragma unroll
                for (int r = 0; r < 4; ++r)
                    outm[(size_t)(rg + r) * 1024 + cmod] = f2bf(acc[i][j][r] + bb);
            }
        }
    }
}

// ---------- 128(M)x64(N) GEMM for out-proj (fp32 out + bias) ----------
// + XOR-swizzled staging/reads (recipe verified in gemm8 since R9 and in the
// R16 128x64 shape: conflicts 0). Unswizzled [row][64] was a 16-way b128
// bank conflict (same pattern measured at 9.4M on the original gemm_bt).
__global__ __launch_bounds__(256) void gemm_out(
    const short* __restrict__ A, const short* __restrict__ Bw,
    const float* __restrict__ bias, float* __restrict__ outf)
{
    __shared__ short As[128 * 64];   // [row][k], XOR-swizzled contents
    __shared__ short Bs[64 * 64];
    const int tid  = threadIdx.x;
    const int w    = tid >> 6, lane = tid & 63;
    const int row0 = blockIdx.y * 128, col0 = blockIdx.x * 64;
    const int lr   = lane & 15, lg = lane >> 4;

    // hoisted per-lane staging address (pre-swizzled source col)
    const int scl = ((lane & 7) * 16) ^ (((lane >> 3) & 7) << 4);
    const char* gA = (const char*)A  + (size_t)(row0 + w * 32) * 2048 + (lane >> 3) * 2048 + scl;
    const char* gB = (const char*)Bw + (size_t)(col0 + w * 16) * 2048 + (lane >> 3) * 2048 + scl;
    const int cswz0 = (lg * 16)      ^ ((lr & 7) << 4);
    const int cswz1 = (64 + lg * 16) ^ ((lr & 7) << 4);

    f32x4 acc[2][4] = {};

    for (int kt = 0; kt < 16; ++kt) {
        __syncthreads();
        #pragma unroll
        for (int rr = 0; rr < 4; ++rr)       // A: wave stages rows w*32 .. w*32+31
            gload16(gA + rr * 16384 + kt * 128, (short*)As + (w * 32 + rr * 8) * 64);
        #pragma unroll
        for (int rr = 0; rr < 2; ++rr)       // B: wave stages rows w*16 .. w*16+15
            gload16(gB + rr * 16384 + kt * 128, (short*)Bs + (w * 16 + rr * 8) * 64);
        __syncthreads();
        #pragma unroll
        for (int kk = 0; kk < 2; ++kk) {
            const int cs = kk ? cswz1 : cswz0;
            bf16x8 af[2], bf[4];
            #pragma unroll
            for (int i = 0; i < 2; ++i)
                af[i] = *(const bf16x8*)((const char*)As + (w * 32 + i * 16 + lr) * 128 + cs);
            #pragma unroll
            for (int j = 0; j < 4; ++j)
                bf[j] = *(const bf16x8*)((const char*)Bs + (j * 16 + lr) * 128 + cs);
            #pragma unroll
            for (int i = 0; i < 2; ++i)
                #pragma unroll
                for (int j = 0; j < 4; ++j)
                    acc[i][j] = __builtin_amdgcn_mfma_f32_16x16x32_bf16(af[i], bf[j], acc[i][j], 0, 0, 0);
        }
    }

    #pragma unroll
    for (int i = 0; i < 2; ++i) {
        const int grb = row0 + w * 32 + i * 16 + lg * 4;
        #pragma unroll
        for (int j = 0; j < 4; ++j) {
            const int cm = col0 + j * 16 + lr;
            const float bb = bias[cm];
            #pragma unroll
            for (int r = 0; r < 4; ++r)
                outf[(size_t)(grb + r) * 1024 + cm] = acc[i][j][r] + bb;
        }
    }
}

// ---------- MFMA sliding-window attention: 128 queries/block, 8 waves ----------
// (unchanged from R14 — verified PASS; V^T col clamped to 248 so zero-P frags
// never over-read past the 256-key row.)
#define KS_ST 72
#define P_ST  168
__global__ __launch_bounds__(512) void attn_mfma(const short* __restrict__ qkv,
                                                 const short* __restrict__ vt,
                                                 short* __restrict__ ctx,
                                                 const float2* __restrict__ tab)
{
    __shared__ char lds[76800];
    short* Ks  = (short*)lds;                    // [256][72] = 36864 B
    short* Pl  = (short*)lds;                    // union: [8][16][168] = 43008 B
    char*  VTs = lds + 43008;                    // [64 d][512 B] = 32768 B
    float* linv = (float*)(lds + 75776);         // [8][16]

    const int tid = threadIdx.x;                 // 0..511
    const int w = tid >> 6, lane = tid & 63;     // 8 waves
    const int g = lane >> 4, l15 = lane & 15;
    const int phys = blockIdx.x;                 // 0..511
    const int bid = (phys & 7) * 64 + (phys >> 3);   // XCD-pack (b,h) groups
    const int b  = bid >> 8;
    const int h  = (bid >> 4) & 15;
    const int qb = bid & 15;
    const int qs = qb << 7;                      // 128-query tile
    const size_t rowbase = (size_t)b * S_LEN;
    const int hc = h << 6;

    // --- stage V^T tile [64 d][256 keys] coalesced, swizzled source ---
    const short* vhead = vt + ((size_t)b * 1024 + h * 64) * VT_ROW + qs;  // +128 pad = key qs-128
    #pragma unroll
    for (int rdx = 0; rdx < 4; ++rdx) {
        const int c = rdx * 512 + tid;           // 0..2047
        const int row = c >> 5, ch = c & 31;     // 64 rows x 32 chunks of 16 B
        const int srcb = (ch * 16) ^ ((row & 7) << 4);
        gload16((const char*)(vhead + (size_t)row * VT_ROW) + srcb, VTs + c * 16);
    }

    // --- stage K with rope (pairs (c, c+32)), zero rows gk<0, stride 72 ---
    #pragma unroll
    for (int it = 0; it < 2; ++it) {
        const int c   = it * 512 + tid;          // 1024 pair-tasks (256 keys x 4)
        const int key = c >> 2;
        const int jb  = (c & 3) << 3;            // 0,8,16,24
        const int gk  = qs - 128 + key;
        const int gkc = gk < 0 ? 0 : gk;
        const short* kb = qkv + (size_t)1 * MAT_ELEMS + (rowbase + gkc) * 1024 + hc;
        const uint4 k1 = *(const uint4*)(kb + jb);
        const uint4 k2 = *(const uint4*)(kb + jb + 32);
        uint4 o1, o2;
        ropePair(k1, k2, tab + (size_t)gkc * 32 + jb, 1.0f, o1, o2);
        if (gk < 0) { o1 = make_uint4(0, 0, 0, 0); o2 = make_uint4(0, 0, 0, 0); }
        *(uint4*)&Ks[key * KS_ST + jb]      = o1;
        *(uint4*)&Ks[key * KS_ST + jb + 32] = o2;
    }
    __syncthreads();                             // K + V^T staged (vmcnt drained)

    // --- Q frags from global, rope + 0.125 scale ---
    const int q = qs + 16 * w + l15;
    const size_t qoff = (rowbase + q) * 1024 + hc;
    const uint4 q1 = *(const uint4*)&qkv[qoff + g * 8];
    const uint4 q2 = *(const uint4*)&qkv[qoff + 32 + g * 8];
    uint4 r1, r2;
    ropePair(q1, q2, tab + (size_t)q * 32 + g * 8, 0.125f, r1, r2);
    const bf16x8 qf0 = __builtin_bit_cast(bf16x8, r1);
    const bf16x8 qf1 = __builtin_bit_cast(bf16x8, r2);

    // --- QK^T: S[q=4g+r][jj=16t+l15]; wave w keys = rows 16w..16w+143 ---
    f32x4 st[9];
    #pragma unroll
    for (int t = 0; t < 9; ++t) {
        const int krow = 16 * w + 16 * t + l15;
        bf16x8 kf0 = *(const bf16x8*)&Ks[krow * KS_ST + g * 8];
        bf16x8 kf1 = *(const bf16x8*)&Ks[krow * KS_ST + 32 + g * 8];
        f32x4 a = {0.f, 0.f, 0.f, 0.f};
        a = __builtin_amdgcn_mfma_f32_16x16x32_bf16(qf0, kf0, a, 0, 0, 0);
        a = __builtin_amdgcn_mfma_f32_16x16x32_bf16(qf1, kf1, a, 0, 0, 0);
        st[t] = a;
    }
    __syncthreads();                             // all Ks reads done; P may overwrite

    // --- softmax (row q = 4g+r held across st[t][r]) + P write (wave-private) ---
    const int jmin = 128 - qs - 16 * w;
    float mrow[4], lsum[4];
    #pragma unroll
    for (int r = 0; r < 4; ++r) mrow[r] = -3.0e38f;
    #pragma unroll
    for (int t = 0; t < 9; ++t) {
        const int jj = 16 * t + l15;
        #pragma unroll
        for (int r = 0; r < 4; ++r) {
            const int qi = 4 * g + r;
            const bool ok = (jj >= qi) && (jj <= qi + 128) && (jj >= jmin);
            if (ok) mrow[r] = fmaxf(mrow[r], st[t][r]);
        }
    }
    #pragma unroll
    for (int r = 0; r < 4; ++r) {
        mrow[r] = fmaxf(mrow[r], __shfl_xor(mrow[r], 1));
        mrow[r] = fmaxf(mrow[r], __shfl_xor(mrow[r], 2));
        mrow[r] = fmaxf(mrow[r], __shfl_xor(mrow[r], 4));
        mrow[r] = fmaxf(mrow[r], __shfl_xor(mrow[r], 8));
        lsum[r] = 0.0f;
    }
    short* Pw = Pl + w * (16 * P_ST);
    #pragma unroll
    for (int t = 0; t < 9; ++t) {
        const int jj = 16 * t + l15;
        #pragma unroll
        for (int r = 0; r < 4; ++r) {
            const int qi = 4 * g + r;
            const bool ok = (jj >= qi) && (jj <= qi + 128) && (jj >= jmin);
            const float p = ok ? __expf(st[t][r] - mrow[r]) : 0.0f;
            lsum[r] += p;
            Pw[qi * P_ST + jj] = f2bf(p);
        }
    }
    {
        short4 z = make_short4(0, 0, 0, 0);
        *(short4*)&Pw[l15 * P_ST + 144 + 4 * g] = z;
    }
    #pragma unroll
    for (int r = 0; r < 4; ++r) {
        lsum[r] += __shfl_xor(lsum[r], 1);
        lsum[r] += __shfl_xor(lsum[r], 2);
        lsum[r] += __shfl_xor(lsum[r], 4);
        lsum[r] += __shfl_xor(lsum[r], 8);
        if (l15 == r) linv[w * 16 + 4 * g + r] = 1.0f / lsum[r];
    }
    // no barrier: P/linv written and read by the same wave

    // --- PV: O^T[d][q] = sum_key V^T[d][key] * P[q][key], V^T from LDS ---
    f32x4 oc[4] = {};
    #pragma unroll
    for (int kc = 0; kc < 5; ++kc) {
        bf16x8 pf = *(const bf16x8*)&Pw[l15 * P_ST + kc * 32 + g * 8];
        int cole = 16 * w + kc * 32 + g * 8;     // V^T element col
        if (cole > 248) cole = 248;              // clamp: only zero-P frags
        const int colb = cole * 2;               // byte col in VTs row
        #pragma unroll
        for (int dt = 0; dt < 4; ++dt) {
            const int row = dt * 16 + l15;
            bf16x8 vf = *(const bf16x8*)(VTs + row * 512 + (colb ^ ((row & 7) << 4)));
            oc[dt] = __builtin_amdgcn_mfma_f32_16x16x32_bf16(vf, pf, oc[dt], 0, 0, 0);
        }
    }

    // --- store: lane holds O[q=l15][dt*16 + 4g + 0..3] ---
    const float inv = linv[w * 16 + l15];
    #pragma unroll
    for (int dt = 0; dt < 4; ++dt) {
        short4 sv;
        sv.x = f2bf(oc[dt][0] * inv);
        sv.y = f2bf(oc[dt][1] * inv);
        sv.z = f2bf(oc[dt][2] * inv);
        sv.w = f2bf(oc[dt][3] * inv);
        *(short4*)&ctx[(rowbase + qs + 16 * w + l15) * 1024 + hc + dt * 16 + 4 * g] = sv;
    }
}

// ---------- launch ----------
extern "C" void kernel_launch(void* const* d_in, const int* in_sizes, int n_in,
                              void* d_out, int out_size, void* d_ws, size_t ws_size,
                              hipStream_t stream) {
    const float* x  = (const float*)d_in[0];
    const float* Wq = (const float*)d_in[1];
    const float* bq = (const float*)d_in[2];
    const float* Wk = (const float*)d_in[3];
    const float* bk = (const float*)d_in[4];
    const float* Wv = (const float*)d_in[5];
    const float* bv = (const float*)d_in[6];
    const float* Wo = (const float*)d_in[7];
    const float* bo = (const float*)d_in[8];

    char* ws = (char*)d_ws;
    short*  xb   = (short*) (ws + 0);          //  8 MiB  x bf16 (dead after gemm8)
    short*  ctx  = (short*) (ws + 0);          //  8 MiB  attn out (reuses xb region)
    short*  wcat = (short*) (ws + 8388608);    //  6 MiB  Wq|Wk|Wv bf16
    short*  wob  = (short*) (ws + 14680064);   //  2 MiB  Wo bf16
    short*  qkv  = (short*) (ws + 16777216);   // 16 MiB  q|k bf16 (roped in attn)
    short*  vt   = (short*) (ws + 33554432);   //  8.5 MiB V^T [2][1024][2176]
    float2* tab  = (float2*)(ws + 42467328);   // 512 KiB rope cos/sin
    float*  bcat = (float*) (ws + 42991616);   // 12 KiB  bq|bk|bv

    prep<<<8192, 256, 0, stream>>>(x, Wq, Wk, Wv, Wo, bq, bk, bv,
                                   xb, wcat, wob, bcat, tab, vt);
    gemm8<<<256, 512, 0, stream>>>(xb, wcat, bcat, qkv, vt);
    attn_mfma<<<512, 512, 0, stream>>>(qkv, vt, ctx, tab);
    gemm_out<<<dim3(16, 32), 256, 0, stream>>>(ctx, wob, bo, (float*)d_out);
}

// Round 18
// 77.523 us; speedup vs baseline: 1.1519x; 1.0051x over previous
//
#include <hip/hip_runtime.h>

// ---------- types ----------
typedef __attribute__((ext_vector_type(8)))  __bf16 bf16x8;
typedef __attribute__((ext_vector_type(4)))  float  f32x4;

// ---------- helpers ----------
__device__ __forceinline__ short f2bf(float f) {
    unsigned u = __builtin_bit_cast(unsigned, f);
    unsigned r = (u + 0x7fffu + ((u >> 16) & 1u)) >> 16;   // RNE
    return (short)r;
}
__device__ __forceinline__ float lo16(unsigned u) { return __builtin_bit_cast(float, u << 16); }
__device__ __forceinline__ float hi16(unsigned u) { return __builtin_bit_cast(float, u & 0xffff0000u); }

__device__ __forceinline__ void gload16(const void* g, void* l) {
    __builtin_amdgcn_global_load_lds(
        (const __attribute__((address_space(1))) unsigned*)g,
        (__attribute__((address_space(3))) unsigned*)l, 16, 0, 0);
}

// rope a pair of 8-element bf16 chunks (packed in uint4), cs8[e] = (cos,sin) for elem e
__device__ __forceinline__ void ropePair(const uint4& a, const uint4& b,
                                         const float2* cs8, float scale,
                                         uint4& oa, uint4& ob) {
    const unsigned au[4] = {a.x, a.y, a.z, a.w}, bu[4] = {b.x, b.y, b.z, b.w};
    unsigned ra[4], rb[4];
    #pragma unroll
    for (int wi = 0; wi < 4; ++wi) {
        const float x1l = lo16(au[wi]), x1h = hi16(au[wi]);
        const float x2l = lo16(bu[wi]), x2h = hi16(bu[wi]);
        const float2 cl = cs8[wi * 2], ch = cs8[wi * 2 + 1];
        const float o1l = (x1l * cl.x - x2l * cl.y) * scale;
        const float o2l = (x1l * cl.y + x2l * cl.x) * scale;
        const float o1h = (x1h * ch.x - x2h * ch.y) * scale;
        const float o2h = (x1h * ch.y + x2h * ch.x) * scale;
        ra[wi] = (unsigned)(unsigned short)f2bf(o1l) | ((unsigned)(unsigned short)f2bf(o1h) << 16);
        rb[wi] = (unsigned)(unsigned short)f2bf(o2l) | ((unsigned)(unsigned short)f2bf(o2h) << 16);
    }
    oa = make_uint4(ra[0], ra[1], ra[2], ra[3]);
    ob = make_uint4(rb[0], rb[1], rb[2], rb[3]);
}

// ---------- constants ----------
#define S_LEN   2048
#define MAT_ELEMS 4194304     // 4096*1024
#define VT_ROW  2176          // 128 zero-pad + 2048 keys
#define VT_MAT  2228224       // 1024 * VT_ROW

// ---------- prep: fp32->bf16 converts + rope table + bias cat + vt pad zero ----------
__global__ __launch_bounds__(256) void prep(
    const float* __restrict__ x,  const float* __restrict__ Wq,
    const float* __restrict__ Wk, const float* __restrict__ Wv,
    const float* __restrict__ Wo, const float* __restrict__ bq,
    const float* __restrict__ bk, const float* __restrict__ bv,
    short* __restrict__ xb, short* __restrict__ wcat, short* __restrict__ wob,
    float* __restrict__ bcat, float2* __restrict__ tab, short* __restrict__ vt)
{
    const int tid = blockIdx.x * 256 + threadIdx.x;   // 0 .. 2M-1 (float4 units)
    const float4* src;
    short* dst;
    if (tid < 1048576) {                       // x: 4M floats
        src = (const float4*)x + tid;  dst = xb + (size_t)tid * 4;
    } else if (tid < 1835008) {                // Wq|Wk|Wv: 3M floats
        const int o = tid - 1048576;
        const int mat = o >> 18;
        const int wi  = o & 262143;
        const float* W = (mat == 0) ? Wq : (mat == 1) ? Wk : Wv;
        src = (const float4*)W + wi;  dst = wcat + (size_t)o * 4;
    } else {                                   // Wo: 1M floats
        const int o = tid - 1835008;
        src = (const float4*)Wo + o;  dst = wob + (size_t)o * 4;
    }
    const float4 v = *src;
    short4 s4 = make_short4(f2bf(v.x), f2bf(v.y), f2bf(v.z), f2bf(v.w));
    *(short4*)dst = s4;

    if (tid < 65536) {                         // rope table [2048][32]
        const int s  = tid >> 5;
        const int jr = tid & 31;
        const float freq = exp2f(-(float)jr * (13.287712379549449f / 32.0f)); // 10000^(-jr/32)
        const float ang  = (float)s * freq;
        tab[tid] = make_float2(cosf(ang), sinf(ang));
    }
    if (tid < 768) {                           // bias cat [3][1024] fp32
        const float* B = (tid < 256) ? bq : (tid < 512) ? bk : bv;
        ((float4*)bcat)[tid] = ((const float4*)B)[tid & 255];
    }
    if (tid < 16384) {                         // zero vt pad: [2048 rows][128]
        const int row = tid >> 3, ch = tid & 7;
        *(uint4*)&vt[(size_t)row * VT_ROW + ch * 8] = make_uint4(0, 0, 0, 0);
    }
}

// ---------- 256(M)x192(N) 2-barrier pipelined GEMM for QKV (B^T layout) ----------
// R14 schedule (lineage optimum). NEW: XCD mapping 8M x 4N per XCD (was
// 2M x 16N): B per XCD = 1.5 MB L2-pinned, each B panel touches only 2 XCDs
// -> L3-fabric traffic ~20 MB vs ~56 MB (theory: gemm8 is fabric-BW-bound;
// total tile traffic 224 MB, FETCH only 28.8 MB -> the rest rode L2/L3).
#define VMC4 do { asm volatile("s_waitcnt vmcnt(4)" ::: "memory"); __builtin_amdgcn_sched_barrier(0); } while (0)
#define VMC0 do { asm volatile("s_waitcnt vmcnt(0)" ::: "memory"); __builtin_amdgcn_sched_barrier(0); } while (0)
#define BAR  __builtin_amdgcn_s_barrier()
#define SB   __builtin_amdgcn_sched_barrier(0)

#define LDA_ALL(T) _Pragma("unroll") for (int ii = 0; ii < 4; ++ii) { \
    aF[ii][0] = ldf(T, fA0, ii * 2048);                                \
    aF[ii][1] = ldf(T, fA1, ii * 2048); }
#define LDB0(T) _Pragma("unroll") for (int jj = 0; jj < 3; ++jj) {    \
    b0[jj][0] = ldf(T, fB0, jj * 2048);                                \
    b0[jj][1] = ldf(T, fB1, jj * 2048); }
#define LDB1(T) _Pragma("unroll") for (int jj = 0; jj < 3; ++jj) {    \
    b1[jj][0] = ldf(T, fB0, (jj + 3) * 2048);                          \
    b1[jj][1] = ldf(T, fB1, (jj + 3) * 2048); }

#define MFMA_HALF(JB, BQ)                                                     \
  __builtin_amdgcn_s_setprio(1);                                              \
  _Pragma("unroll") for (int ii = 0; ii < 4; ++ii)                            \
    _Pragma("unroll") for (int jj = 0; jj < 3; ++jj) {                        \
      acc[ii][(JB)+jj] = __builtin_amdgcn_mfma_f32_16x16x32_bf16(             \
          aF[ii][0], BQ[jj][0], acc[ii][(JB)+jj], 0, 0, 0);                   \
      acc[ii][(JB)+jj] = __builtin_amdgcn_mfma_f32_16x16x32_bf16(             \
          aF[ii][1], BQ[jj][1], acc[ii][(JB)+jj], 0, 0, 0);                   \
    }                                                                         \
  __builtin_amdgcn_s_setprio(0);

#define STGA(KT_, TILE) _Pragma("unroll") for (int g = 0; g < 4; ++g)  \
    gload16(gA + g * 16384 + (KT_) * 128, (TILE) + (w * 32 + g * 8) * 64);
#define STGB(KT_, TILE) _Pragma("unroll") for (int g = 0; g < 3; ++g)  \
    gload16(gB + g * 16384 + (KT_) * 128, (TILE) + (w * 24 + g * 8) * 64);

#define KT2(CA, CB, SBSTG, SASTG, WSTMT)              \
  LDA_ALL(CA); LDB0(CB); SBSTG;                       \
  MFMA_HALF(0, b0); SB; LDB1(CB); SB;                 \
  BAR;                                                \
  SASTG;                                              \
  MFMA_HALF(3, b1); WSTMT; BAR;

__global__ __launch_bounds__(512) void gemm8(
    const short* __restrict__ A,   // [4096][1024]
    const short* __restrict__ Bw,  // [3072][1024] (row = out col)
    const float* __restrict__ bias,// [3072]
    short* __restrict__ outb,      // Q,K: [2][4096][1024]
    short* __restrict__ vt)        // V^T: [2][1024][2176] (128-key zero pad front)
{
    __shared__ short lds[57344];               // 112 KiB
    short* const Ab0 = lds;                    // [256][64]
    short* const Bb0 = lds + 16384;            // [192][64]
    short* const Ab1 = lds + 28672;
    short* const Bb1 = lds + 45056;

    const int tid = threadIdx.x;
    const int w = tid >> 6, lane = tid & 63;
    const int wm = w >> 1, wn = w & 1;         // 4M x 2N
    const int lr = lane & 15, lg = lane >> 4;

    // XCD mapping: per XCD 8 M-rows x 4 N-cols (bijective; XCD grid 2x4).
    // B working set/XCD = 4 panels = 1.5 MB (L2-resident); each B panel read
    // by 2 XCDs, each A panel by 4 (concurrently -> L2 temporal hits).
    const int wg  = blockIdx.x;
    const int xcd = wg & 7, i5 = wg >> 3;      // i5 in 0..31
    const int by  = (xcd >> 2) * 8 + (i5 >> 2);
    const int bx  = (xcd & 3) * 4 + (i5 & 3);
    const int row0 = by * 256, col0 = bx * 192;

    // ---- hoisted per-lane invariant addressing ----
    const int scl  = ((lane & 7) * 16) ^ (((lane >> 3) & 7) << 4);
    const int goff = (lane >> 3) * 2048 + scl;
    const char* gA = (const char*)A  + (size_t)(row0 + w * 32) * 2048 + goff;
    const char* gB = (const char*)Bw + (size_t)(col0 + w * 24) * 2048 + goff;
    const int cswz0 = (lg * 16)      ^ ((lr & 7) << 4);
    const int cswz1 = (64 + lg * 16) ^ ((lr & 7) << 4);
    const int fA0 = (wm * 64 + lr) * 128 + cswz0;
    const int fA1 = (wm * 64 + lr) * 128 + cswz1;
    const int fB0 = (wn * 96 + lr) * 128 + cswz0;
    const int fB1 = (wn * 96 + lr) * 128 + cswz1;

    auto ldf = [&](const short* buf, int voff, int imm) -> bf16x8 {
        return *(const bf16x8*)((const char*)buf + voff + imm);
    };

    f32x4 acc[4][6] = {};
    bf16x8 aF[4][2], b0[3][2], b1[3][2];

    // prologue: tile0 A,B + tile1 A
    STGA(0, Ab0); STGB(0, Bb0); STGA(1, Ab1);
    VMC4;
    BAR;

    #pragma unroll 1
    for (int it = 0; it < 7; ++it) {
        const int t0 = it * 2;
        KT2(Ab0, Bb0, STGB(t0 + 1, Bb1), STGA(t0 + 2, Ab0), VMC4)
        const int t1 = t0 + 1;
        KT2(Ab1, Bb1, STGB(t1 + 1, Bb0), STGA(t1 + 2, Ab1), VMC4)
    }
    KT2(Ab0, Bb0, STGB(15, Bb1), {}, VMC0)
    KT2(Ab1, Bb1, {}, {}, {})

    // epilogue: per-frag mat select (16-aligned frag base -> wave-uniform)
    #pragma unroll
    for (int j = 0; j < 6; ++j) {
        const int base_cm = col0 + wn * 96 + j * 16;
        const int matj = base_cm >> 10;
        const float bb = bias[base_cm + lr];
        if (matj == 2) {                       // V^T: vt[b][dg][128+key]
            const size_t dgo = (size_t)(base_cm - 2048 + lr) * VT_ROW;
            #pragma unroll
            for (int i = 0; i < 4; ++i) {
                const int rg = row0 + wm * 64 + i * 16 + lg * 4;
                const int bq_ = rg >> 11, key = rg & 2047;
                short4 sv;
                sv.x = f2bf(acc[i][j][0] + bb); sv.y = f2bf(acc[i][j][1] + bb);
                sv.z = f2bf(acc[i][j][2] + bb); sv.w = f2bf(acc[i][j][3] + bb);
                *(short4*)&vt[(size_t)bq_ * VT_MAT + dgo + 128 + key] = sv;
            }
        } else {                               // Q/K rows
            short* outm = outb + (size_t)matj * MAT_ELEMS;
            const int cmod = (base_cm & 1023) + lr;
            #pragma unroll
            for (int i = 0; i < 4; ++i) {
                const int rg = row0 + wm * 64 + i * 16 + lg * 4;
                #pragma unroll
                for (int r = 0; r < 4; ++r)
                    outm[(size_t)(rg + r) * 1024 + cmod] = f2bf(acc[i][j][r] + bb);
            }
        }
    }
}

// ---------- 128(M)x64(N) GEMM for out-proj (fp32 out + bias) ----------
// XOR-swizzled staging/reads (R17: conflicts eliminated, -3 us).
__global__ __launch_bounds__(256) void gemm_out(
    const short* __restrict__ A, const short* __restrict__ Bw,
    const float* __restrict__ bias, float* __restrict__ outf)
{
    __shared__ short As[128 * 64];   // [row][k], XOR-swizzled contents
    __shared__ short Bs[64 * 64];
    const int tid  = threadIdx.x;
    const int w    = tid >> 6, lane = tid & 63;
    const int row0 = blockIdx.y * 128, col0 = blockIdx.x * 64;
    const int lr   = lane & 15, lg = lane >> 4;

    // hoisted per-lane staging address (pre-swizzled source col)
    const int scl = ((lane & 7) * 16) ^ (((lane >> 3) & 7) << 4);
    const char* gA = (const char*)A  + (size_t)(row0 + w * 32) * 2048 + (lane >> 3) * 2048 + scl;
    const char* gB = (const char*)Bw + (size_t)(col0 + w * 16) * 2048 + (lane >> 3) * 2048 + scl;
    const int cswz0 = (lg * 16)      ^ ((lr & 7) << 4);
    const int cswz1 = (64 + lg * 16) ^ ((lr & 7) << 4);

    f32x4 acc[2][4] = {};

    for (int kt = 0; kt < 16; ++kt) {
        __syncthreads();
        #pragma unroll
        for (int rr = 0; rr < 4; ++rr)       // A: wave stages rows w*32 .. w*32+31
            gload16(gA + rr * 16384 + kt * 128, (short*)As + (w * 32 + rr * 8) * 64);
        #pragma unroll
        for (int rr = 0; rr < 2; ++rr)       // B: wave stages rows w*16 .. w*16+15
            gload16(gB + rr * 16384 + kt * 128, (short*)Bs + (w * 16 + rr * 8) * 64);
        __syncthreads();
        #pragma unroll
        for (int kk = 0; kk < 2; ++kk) {
            const int cs = kk ? cswz1 : cswz0;
            bf16x8 af[2], bf[4];
            #pragma unroll
            for (int i = 0; i < 2; ++i)
                af[i] = *(const bf16x8*)((const char*)As + (w * 32 + i * 16 + lr) * 128 + cs);
            #pragma unroll
            for (int j = 0; j < 4; ++j)
                bf[j] = *(const bf16x8*)((const char*)Bs + (j * 16 + lr) * 128 + cs);
            #pragma unroll
            for (int i = 0; i < 2; ++i)
                #pragma unroll
                for (int j = 0; j < 4; ++j)
                    acc[i][j] = __builtin_amdgcn_mfma_f32_16x16x32_bf16(af[i], bf[j], acc[i][j], 0, 0, 0);
        }
    }

    #pragma unroll
    for (int i = 0; i < 2; ++i) {
        const int grb = row0 + w * 32 + i * 16 + lg * 4;
        #pragma unroll
        for (int j = 0; j < 4; ++j) {
            const int cm = col0 + j * 16 + lr;
            const float bb = bias[cm];
            #pragma unroll
            for (int r = 0; r < 4; ++r)
                outf[(size_t)(grb + r) * 1024 + cm] = acc[i][j][r] + bb;
        }
    }
}

// ---------- MFMA sliding-window attention: 128 queries/block, 8 waves ----------
// (unchanged from R14 — verified PASS; V^T col clamped to 248 so zero-P frags
// never over-read past the 256-key row.)
#define KS_ST 72
#define P_ST  168
__global__ __launch_bounds__(512) void attn_mfma(const short* __restrict__ qkv,
                                                 const short* __restrict__ vt,
                                                 short* __restrict__ ctx,
                                                 const float2* __restrict__ tab)
{
    __shared__ char lds[76800];
    short* Ks  = (short*)lds;                    // [256][72] = 36864 B
    short* Pl  = (short*)lds;                    // union: [8][16][168] = 43008 B
    char*  VTs = lds + 43008;                    // [64 d][512 B] = 32768 B
    float* linv = (float*)(lds + 75776);         // [8][16]

    const int tid = threadIdx.x;                 // 0..511
    const int w = tid >> 6, lane = tid & 63;     // 8 waves
    const int g = lane >> 4, l15 = lane & 15;
    const int phys = blockIdx.x;                 // 0..511
    const int bid = (phys & 7) * 64 + (phys >> 3);   // XCD-pack (b,h) groups
    const int b  = bid >> 8;
    const int h  = (bid >> 4) & 15;
    const int qb = bid & 15;
    const int qs = qb << 7;                      // 128-query tile
    const size_t rowbase = (size_t)b * S_LEN;
    const int hc = h << 6;

    // --- stage V^T tile [64 d][256 keys] coalesced, swizzled source ---
    const short* vhead = vt + ((size_t)b * 1024 + h * 64) * VT_ROW + qs;  // +128 pad = key qs-128
    #pragma unroll
    for (int rdx = 0; rdx < 4; ++rdx) {
        const int c = rdx * 512 + tid;           // 0..2047
        const int row = c >> 5, ch = c & 31;     // 64 rows x 32 chunks of 16 B
        const int srcb = (ch * 16) ^ ((row & 7) << 4);
        gload16((const char*)(vhead + (size_t)row * VT_ROW) + srcb, VTs + c * 16);
    }

    // --- stage K with rope (pairs (c, c+32)), zero rows gk<0, stride 72 ---
    #pragma unroll
    for (int it = 0; it < 2; ++it) {
        const int c   = it * 512 + tid;          // 1024 pair-tasks (256 keys x 4)
        const int key = c >> 2;
        const int jb  = (c & 3) << 3;            // 0,8,16,24
        const int gk  = qs - 128 + key;
        const int gkc = gk < 0 ? 0 : gk;
        const short* kb = qkv + (size_t)1 * MAT_ELEMS + (rowbase + gkc) * 1024 + hc;
        const uint4 k1 = *(const uint4*)(kb + jb);
        const uint4 k2 = *(const uint4*)(kb + jb + 32);
        uint4 o1, o2;
        ropePair(k1, k2, tab + (size_t)gkc * 32 + jb, 1.0f, o1, o2);
        if (gk < 0) { o1 = make_uint4(0, 0, 0, 0); o2 = make_uint4(0, 0, 0, 0); }
        *(uint4*)&Ks[key * KS_ST + jb]      = o1;
        *(uint4*)&Ks[key * KS_ST + jb + 32] = o2;
    }
    __syncthreads();                             // K + V^T staged (vmcnt drained)

    // --- Q frags from global, rope + 0.125 scale ---
    const int q = qs + 16 * w + l15;
    const size_t qoff = (rowbase + q) * 1024 + hc;
    const uint4 q1 = *(const uint4*)&qkv[qoff + g * 8];
    const uint4 q2 = *(const uint4*)&qkv[qoff + 32 + g * 8];
    uint4 r1, r2;
    ropePair(q1, q2, tab + (size_t)q * 32 + g * 8, 0.125f, r1, r2);
    const bf16x8 qf0 = __builtin_bit_cast(bf16x8, r1);
    const bf16x8 qf1 = __builtin_bit_cast(bf16x8, r2);

    // --- QK^T: S[q=4g+r][jj=16t+l15]; wave w keys = rows 16w..16w+143 ---
    f32x4 st[9];
    #pragma unroll
    for (int t = 0; t < 9; ++t) {
        const int krow = 16 * w + 16 * t + l15;
        bf16x8 kf0 = *(const bf16x8*)&Ks[krow * KS_ST + g * 8];
        bf16x8 kf1 = *(const bf16x8*)&Ks[krow * KS_ST + 32 + g * 8];
        f32x4 a = {0.f, 0.f, 0.f, 0.f};
        a = __builtin_amdgcn_mfma_f32_16x16x32_bf16(qf0, kf0, a, 0, 0, 0);
        a = __builtin_amdgcn_mfma_f32_16x16x32_bf16(qf1, kf1, a, 0, 0, 0);
        st[t] = a;
    }
    __syncthreads();                             // all Ks reads done; P may overwrite

    // --- softmax (row q = 4g+r held across st[t][r]) + P write (wave-private) ---
    const int jmin = 128 - qs - 16 * w;
    float mrow[4], lsum[4];
    #pragma unroll
    for (int r = 0; r < 4; ++r) mrow[r] = -3.0e38f;
    #pragma unroll
    for (int t = 0; t < 9; ++t) {
        const int jj = 16 * t + l15;
        #pragma unroll
        for (int r = 0; r < 4; ++r) {
            const int qi = 4 * g + r;
            const bool ok = (jj >= qi) && (jj <= qi + 128) && (jj >= jmin);
            if (ok) mrow[r] = fmaxf(mrow[r], st[t][r]);
        }
    }
    #pragma unroll
    for (int r = 0; r < 4; ++r) {
        mrow[r] = fmaxf(mrow[r], __shfl_xor(mrow[r], 1));
        mrow[r] = fmaxf(mrow[r], __shfl_xor(mrow[r], 2));
        mrow[r] = fmaxf(mrow[r], __shfl_xor(mrow[r], 4));
        mrow[r] = fmaxf(mrow[r], __shfl_xor(mrow[r], 8));
        lsum[r] = 0.0f;
    }
    short* Pw = Pl + w * (16 * P_ST);
    #pragma unroll
    for (int t = 0; t < 9; ++t) {
        const int jj = 16 * t + l15;
        #pragma unroll
        for (int r = 0; r < 4; ++r) {
            const int qi = 4 * g + r;
            const bool ok = (jj >= qi) && (jj <= qi + 128) && (jj >= jmin);
            const float p = ok ? __expf(st[t][r] - mrow[r]) : 0.0f;
            lsum[r] += p;
            Pw[qi * P_ST + jj] = f2bf(p);
        }
    }
    {
        short4 z = make_short4(0, 0, 0, 0);
        *(short4*)&Pw[l15 * P_ST + 144 + 4 * g] = z;
    }
    #pragma unroll
    for (int r = 0; r < 4; ++r) {
        lsum[r] += __shfl_xor(lsum[r], 1);
        lsum[r] += __shfl_xor(lsum[r], 2);
        lsum[r] += __shfl_xor(lsum[r], 4);
        lsum[r] += __shfl_xor(lsum[r], 8);
        if (l15 == r) linv[w * 16 + 4 * g + r] = 1.0f / lsum[r];
    }
    // no barrier: P/linv written and read by the same wave

    // --- PV: O^T[d][q] = sum_key V^T[d][key] * P[q][key], V^T from LDS ---
    f32x4 oc[4] = {};
    #pragma unroll
    for (int kc = 0; kc < 5; ++kc) {
        bf16x8 pf = *(const bf16x8*)&Pw[l15 * P_ST + kc * 32 + g * 8];
        int cole = 16 * w + kc * 32 + g * 8;     // V^T element col
        if (cole > 248) cole = 248;              // clamp: only zero-P frags
        const int colb = cole * 2;               // byte col in VTs row
        #pragma unroll
        for (int dt = 0; dt < 4; ++dt) {
            const int row = dt * 16 + l15;
            bf16x8 vf = *(const bf16x8*)(VTs + row * 512 + (colb ^ ((row & 7) << 4)));
            oc[dt] = __builtin_amdgcn_mfma_f32_16x16x32_bf16(vf, pf, oc[dt], 0, 0, 0);
        }
    }

    // --- store: lane holds O[q=l15][dt*16 + 4g + 0..3] ---
    const float inv = linv[w * 16 + l15];
    #pragma unroll
    for (int dt = 0; dt < 4; ++dt) {
        short4 sv;
        sv.x = f2bf(oc[dt][0] * inv);
        sv.y = f2bf(oc[dt][1] * inv);
        sv.z = f2bf(oc[dt][2] * inv);
        sv.w = f2bf(oc[dt][3] * inv);
        *(short4*)&ctx[(rowbase + qs + 16 * w + l15) * 1024 + hc + dt * 16 + 4 * g] = sv;
    }
}

// ---------- launch ----------
extern "C" void kernel_launch(void* const* d_in, const int* in_sizes, int n_in,
                              void* d_out, int out_size, void* d_ws, size_t ws_size,
                              hipStream_t stream) {
    const float* x  = (const float*)d_in[0];
    const float* Wq = (const float*)d_in[1];
    const float* bq = (const float*)d_in[2];
    const float* Wk = (const float*)d_in[3];
    const float* bk = (const float*)d_in[4];
    const float* Wv = (const float*)d_in[5];
    const float* bv = (const float*)d_in[6];
    const float* Wo = (const float*)d_in[7];
    const float* bo = (const float*)d_in[8];

    char* ws = (char*)d_ws;
    short*  xb   = (short*) (ws + 0);          //  8 MiB  x bf16 (dead after gemm8)
    short*  ctx  = (short*) (ws + 0);          //  8 MiB  attn out (reuses xb region)
    short*  wcat = (short*) (ws + 8388608);    //  6 MiB  Wq|Wk|Wv bf16
    short*  wob  = (short*) (ws + 14680064);   //  2 MiB  Wo bf16
    short*  qkv  = (short*) (ws + 16777216);   // 16 MiB  q|k bf16 (roped in attn)
    short*  vt   = (short*) (ws + 33554432);   //  8.5 MiB V^T [2][1024][2176]
    float2* tab  = (float2*)(ws + 42467328);   // 512 KiB rope cos/sin
    float*  bcat = (float*) (ws + 42991616);   // 12 KiB  bq|bk|bv

    prep<<<8192, 256, 0, stream>>>(x, Wq, Wk, Wv, Wo, bq, bk, bv,
                                   xb, wcat, wob, bcat, tab, vt);
    gemm8<<<256, 512, 0, stream>>>(xb, wcat, bcat, qkv, vt);
    attn_mfma<<<512, 512, 0, stream>>>(qkv, vt, ctx, tab);
    gemm_out<<<dim3(16, 32), 256, 0, stream>>>(ctx, wob, bo, (float*)d_out);
}